// Round 1
// baseline (43318.958 us; speedup 1.0000x reference)
//
#include <hip/hip_runtime.h>
#include <hip/hip_bf16.h>

// MaskedLSTM: B=128 S=1024 I=512 H=512
// out = [B,S,H] f32  ++  hT [1,B,H] f32  ++  cT [1,B,H] f32
//
// Design:
//  - i-gate is computed but UNUSED in the reference -> skip Wi/Wi_m/Ui/Ui_m/bi.
//  - Hoist x-projections: xg_g[b,t,:] = sigmoid(x W_m^T) * (x W^T)  (3 pairs: f,o,c), bf16 MFMA.
//  - Recurrence: persistent cooperative kernel, 16 teams x 16 blocks.
//    block owns 8 batch rows x 32 cols; U-weights resident in VGPRs (48 frags/wave).
//    h exchanged via global double buffer + per-team per-step counter barrier.

typedef __attribute__((ext_vector_type(8))) short short8;
typedef __attribute__((ext_vector_type(4))) float floatx4;
typedef unsigned short ushort_t;

static constexpr size_t kMat   = 512 * 512;              // 262144 elems
static constexpr size_t O_W    = 0;                      // 12 mats bf16: 6291456 B
static constexpr size_t O_XGO  = 12 * kMat * 2;          // 6291456
static constexpr size_t O_XGC  = O_XGO + 134217728ull;   // 140509184
static constexpr size_t O_XGF  = O_XGC + 134217728ull;   // 274726912 (last-step xg_f, B*H bf16)
static constexpr size_t O_HB   = O_XGF + 131072ull;      // 274857984 (16 teams * 2 * 16 * 512 bf16)
static constexpr size_t O_CNT  = O_HB + 524288ull;       // 275382272 (16*1024 u32)
static constexpr size_t WS_NEED = O_CNT + 65536ull;      // ~263 MB

__device__ __forceinline__ ushort_t f2bf(float f) {
  unsigned u = __float_as_uint(f);
  u = (u + 0x7FFFu + ((u >> 16) & 1u)) >> 16;
  return (ushort_t)u;
}
__device__ __forceinline__ float bf2f(ushort_t h) {
  return __uint_as_float(((unsigned)h) << 16);
}
__device__ __forceinline__ float sigf(float x) { return 1.0f / (1.0f + __expf(-x)); }

struct Ptrs12 { const float* p[12]; };

// ---------------- prep: weights fp32->bf16, zero hbuf+cnt ----------------
__global__ void k_prep(Ptrs12 a, ushort_t* __restrict__ wbf, unsigned* __restrict__ zr) {
  unsigned idx = blockIdx.x * 256u + threadIdx.x;
  const unsigned WTOT = 12u * 262144u;
  if (idx < WTOT) {
    wbf[idx] = f2bf(a.p[idx >> 18][idx & 262143u]);
  } else {
    zr[idx - WTOT] = 0u;  // grid sized exactly: (WTOT + 147456)/256 blocks
  }
}

// ---------------- x-projection masked-linear GEMM ----------------
// grid (1024, 4, 3): M-tile 128, N-tile 128, pair p in {f,o,c}
__global__ __launch_bounds__(256, 2) void k_xgemm(
    const float* __restrict__ x, const ushort_t* __restrict__ wbf,
    ushort_t* __restrict__ xgo, ushort_t* __restrict__ xgc,
    ushort_t* __restrict__ xgf_last, ushort_t* out_xgf) {
  __shared__ ushort_t At[128][64];
  __shared__ ushort_t Bt[2][128][64];
  const int p  = blockIdx.z;
  const int R0 = blockIdx.x * 128;
  const int n0 = blockIdx.y * 128;
  const ushort_t* Wmain = wbf + (size_t)(2 * p) * kMat;
  const ushort_t* Wmask = wbf + (size_t)(2 * p + 1) * kMat;
  const int tid = threadIdx.x;
  const int lane = tid & 63, w = tid >> 6;
  const int wr = w >> 1, wc = w & 1;
  const int sr = tid >> 1, sh = tid & 1;

  floatx4 accM[4][4], accK[4][4];
#pragma unroll
  for (int mt = 0; mt < 4; ++mt)
#pragma unroll
    for (int nt = 0; nt < 4; ++nt) {
      accM[mt][nt] = (floatx4){0.f, 0.f, 0.f, 0.f};
      accK[mt][nt] = (floatx4){0.f, 0.f, 0.f, 0.f};
    }

  for (int kb = 0; kb < 8; ++kb) {
    __syncthreads();
    // stage A: x fp32 -> bf16
    const float* xa = x + (size_t)(R0 + sr) * 512 + kb * 64 + sh * 32;
#pragma unroll
    for (int q = 0; q < 4; ++q) {
      float4 v0 = *reinterpret_cast<const float4*>(xa + q * 8);
      float4 v1 = *reinterpret_cast<const float4*>(xa + q * 8 + 4);
      short8 s;
      s[0] = (short)f2bf(v0.x); s[1] = (short)f2bf(v0.y);
      s[2] = (short)f2bf(v0.z); s[3] = (short)f2bf(v0.w);
      s[4] = (short)f2bf(v1.x); s[5] = (short)f2bf(v1.y);
      s[6] = (short)f2bf(v1.z); s[7] = (short)f2bf(v1.w);
      *reinterpret_cast<short8*>(&At[sr][sh * 32 + q * 8]) = s;
    }
    // stage B: both weight matrices (already bf16)
#pragma unroll
    for (int m2 = 0; m2 < 2; ++m2) {
      const ushort_t* src = (m2 ? Wmask : Wmain) + (size_t)(n0 + sr) * 512 + kb * 64 + sh * 32;
#pragma unroll
      for (int q = 0; q < 4; ++q)
        *reinterpret_cast<short8*>(&Bt[m2][sr][sh * 32 + q * 8]) =
            *reinterpret_cast<const short8*>(src + q * 8);
    }
    __syncthreads();
#pragma unroll
    for (int ks = 0; ks < 2; ++ks) {
      const int ko = ks * 32 + (lane >> 4) * 8;
      short8 a[4], b0[4], b1[4];
#pragma unroll
      for (int mt = 0; mt < 4; ++mt)
        a[mt] = *reinterpret_cast<const short8*>(&At[wr * 64 + mt * 16 + (lane & 15)][ko]);
#pragma unroll
      for (int nt = 0; nt < 4; ++nt) {
        b0[nt] = *reinterpret_cast<const short8*>(&Bt[0][wc * 64 + nt * 16 + (lane & 15)][ko]);
        b1[nt] = *reinterpret_cast<const short8*>(&Bt[1][wc * 64 + nt * 16 + (lane & 15)][ko]);
      }
#pragma unroll
      for (int mt = 0; mt < 4; ++mt)
#pragma unroll
        for (int nt = 0; nt < 4; ++nt) {
          accM[mt][nt] = __builtin_amdgcn_mfma_f32_16x16x32_bf16(a[mt], b0[nt], accM[mt][nt], 0, 0, 0);
          accK[mt][nt] = __builtin_amdgcn_mfma_f32_16x16x32_bf16(a[mt], b1[nt], accK[mt][nt], 0, 0, 0);
        }
    }
  }
  // epilogue: sigmoid(mask) * main, store bf16
#pragma unroll
  for (int mt = 0; mt < 4; ++mt)
#pragma unroll
    for (int nt = 0; nt < 4; ++nt)
#pragma unroll
      for (int r = 0; r < 4; ++r) {
        float val = sigf(accK[mt][nt][r]) * accM[mt][nt][r];
        int row = R0 + wr * 64 + mt * 16 + (lane >> 4) * 4 + r;   // flattened b*S+t
        int col = n0 + wc * 64 + nt * 16 + (lane & 15);
        ushort_t bv = f2bf(val);
        if (p == 1) {
          xgo[(size_t)row * 512 + col] = bv;
        } else if (p == 2) {
          xgc[(size_t)row * 512 + col] = bv;
        } else {
          int t = row & 1023;
          if (t == 1023) xgf_last[(row >> 10) * 512 + col] = bv;
          else out_xgf[(size_t)(row + 1) * 1024 + 512 + col] = bv;  // upper half of f32 slot t+1
        }
      }
}

// ---------------- recurrence: persistent, 16 teams x 16 blocks ----------------
__global__ __launch_bounds__(256, 1) void k_recur(
    const ushort_t* __restrict__ ubf,
    const ushort_t* __restrict__ xgo, const ushort_t* __restrict__ xgc,
    const ushort_t* __restrict__ xgf_last,
    ushort_t* hbuf, unsigned* cnt,
    const float* __restrict__ bfp, const float* __restrict__ bop, const float* __restrict__ bcp,
    float* out) {
  __shared__ float comb[12][8][16];
  const int bid = blockIdx.x;
  const int team = bid >> 4;     // 16 teams of 8 batch rows
  const int member = bid & 15;   // 16 blocks/team, 32 cols each
  const int tid = threadIdx.x;
  const int lane = tid & 63, w = tid >> 6;

  // ---- resident U weight fragments: wave w owns chunks {w, w+4, w+8} ----
  short8 uw[3][16];
#pragma unroll
  for (int i = 0; i < 3; ++i) {
    const int c = w + 4 * i;
    const int m = c % 6, ct = c / 6;
    const int row = member * 32 + ct * 16 + (lane & 15);
    const ushort_t* src = ubf + (size_t)m * kMat + (size_t)row * 512 + (lane >> 4) * 8;
#pragma unroll
    for (int kf = 0; kf < 16; ++kf)
      uw[i][kf] = *reinterpret_cast<const short8*>(src + kf * 32);
  }

  // elementwise identity: thread -> (row er, col ej)
  const int er = tid >> 5;          // 0..7
  const int ej = tid & 31;          // 0..31
  const int ect = ej >> 4, ejj = ej & 15;
  const int col = member * 32 + ej;
  const int b = team * 8 + er;
  const float bfv = bfp[col], bov = bop[col], bcv = bcp[col];
  float cp = 0.0f;

  ushort_t* hb = hbuf + (size_t)team * (2 * 16 * 512);
  unsigned* tcnt = cnt + team * 1024;
  const ushort_t* out_us = reinterpret_cast<const ushort_t*>(out);
  int cur = 0;

  for (int t = 0; t < 1024; ++t) {
    const ushort_t* hc = hb + cur * (16 * 512);
    // A fragments: h_prev [16(pad) x 512] bf16
    short8 af[16];
    const ushort_t* asrc = hc + (lane & 15) * 512 + (lane >> 4) * 8;
#pragma unroll
    for (int kf = 0; kf < 16; ++kf)
      af[kf] = *reinterpret_cast<const short8*>(asrc + kf * 32);

    floatx4 acc[3];
#pragma unroll
    for (int i = 0; i < 3; ++i) acc[i] = (floatx4){0.f, 0.f, 0.f, 0.f};
#pragma unroll
    for (int kf = 0; kf < 16; ++kf)
#pragma unroll
      for (int i = 0; i < 3; ++i)
        acc[i] = __builtin_amdgcn_mfma_f32_16x16x32_bf16(af[kf], uw[i][kf], acc[i], 0, 0, 0);

    // prefetch x-projections (hide HBM latency under LDS combine)
    const size_t bt = (size_t)b * 1024 + t;
    float xov = bf2f(xgo[bt * 512 + col]);
    float xcv = bf2f(xgc[bt * 512 + col]);
    float xfv = (t == 1023) ? bf2f(xgf_last[b * 512 + col])
                            : bf2f(out_us[(bt + 1) * 1024 + 512 + col]);

    // scatter acc rows 0..7 to LDS for the pair-combine
    if (lane < 32) {
      const int rr = (lane >> 4) * 4;
#pragma unroll
      for (int i = 0; i < 3; ++i) {
        const int c = w + 4 * i;
#pragma unroll
        for (int r = 0; r < 4; ++r) comb[c][rr + r][lane & 15] = acc[i][r];
      }
    }
    __syncthreads();

    const float hUf  = comb[ect * 6 + 0][er][ejj];
    const float hUfm = comb[ect * 6 + 1][er][ejj];
    const float hUo  = comb[ect * 6 + 2][er][ejj];
    const float hUom = comb[ect * 6 + 3][er][ejj];
    const float hUc  = comb[ect * 6 + 4][er][ejj];
    const float hUcm = comb[ect * 6 + 5][er][ejj];

    const float fg = sigf(sigf(hUfm) * hUf + xfv + bfv);
    const float og = sigf(sigf(hUom) * hUo + xov + bov);
    const float cn = fg * cp + tanhf(sigf(hUcm) * hUc + xcv + bcv);
    const float hv = og * cn;
    cp = cn;

    out[bt * 512 + col] = hv;                       // y (overwrites consumed xg_f slot)
    ushort_t* hn = hb + (cur ^ 1) * (16 * 512);
    hn[er * 512 + col] = f2bf(hv);
    if (t == 1023) {
      out[67108864ull + (size_t)b * 512 + col] = hv;            // hT
      out[67108864ull + 65536ull + (size_t)b * 512 + col] = cn; // cT
    }

    // team barrier (release h, acquire others' h)
    __threadfence();
    __syncthreads();
    if (tid == 0) {
      __hip_atomic_fetch_add(&tcnt[t], 1u, __ATOMIC_RELEASE, __HIP_MEMORY_SCOPE_AGENT);
      while (__hip_atomic_load(&tcnt[t], __ATOMIC_RELAXED, __HIP_MEMORY_SCOPE_AGENT) < 16u)
        __builtin_amdgcn_s_sleep(2);
    }
    __syncthreads();
    __threadfence();
    cur ^= 1;
  }
}

extern "C" void kernel_launch(void* const* d_in, const int* in_sizes, int n_in,
                              void* d_out, int out_size, void* d_ws, size_t ws_size,
                              hipStream_t stream) {
  (void)in_sizes; (void)n_in; (void)out_size; (void)ws_size;
  // d_in order: 0 Wf,1 Wf_m,2 Wi,3 Wi_m,4 Wo,5 Wo_m,6 Wc,7 Wc_m,
  //             8 Uf,9 Uf_m,10 Ui,11 Ui_m,12 Uo,13 Uo_m,14 Uc,15 Uc_m,
  //             16 bf,17 bi,18 bo,19 bc, 20 x
  char* ws = (char*)d_ws;
  ushort_t* wbf = (ushort_t*)(ws + O_W);
  const ushort_t* ubf = wbf + 6 * kMat;
  ushort_t* xgo = (ushort_t*)(ws + O_XGO);
  ushort_t* xgc = (ushort_t*)(ws + O_XGC);
  ushort_t* xgfl = (ushort_t*)(ws + O_XGF);
  ushort_t* hbuf = (ushort_t*)(ws + O_HB);
  unsigned* cnt = (unsigned*)(ws + O_CNT);

  Ptrs12 pa;
  pa.p[0] = (const float*)d_in[0];  pa.p[1] = (const float*)d_in[1];   // Wf, Wf_m
  pa.p[2] = (const float*)d_in[4];  pa.p[3] = (const float*)d_in[5];   // Wo, Wo_m
  pa.p[4] = (const float*)d_in[6];  pa.p[5] = (const float*)d_in[7];   // Wc, Wc_m
  pa.p[6] = (const float*)d_in[8];  pa.p[7] = (const float*)d_in[9];   // Uf, Uf_m
  pa.p[8] = (const float*)d_in[12]; pa.p[9] = (const float*)d_in[13];  // Uo, Uo_m
  pa.p[10] = (const float*)d_in[14]; pa.p[11] = (const float*)d_in[15]; // Uc, Uc_m

  hipLaunchKernelGGL(k_prep, dim3((12u * 262144u + 147456u) / 256u), dim3(256), 0, stream,
                     pa, wbf, (unsigned*)(ws + O_HB));
  hipLaunchKernelGGL(k_xgemm, dim3(1024, 4, 3), dim3(256), 0, stream,
                     (const float*)d_in[20], wbf, xgo, xgc, xgfl, (ushort_t*)d_out);

  const ushort_t* a_ubf = ubf;
  const ushort_t* a_xgo = xgo;
  const ushort_t* a_xgc = xgc;
  const ushort_t* a_xgfl = xgfl;
  ushort_t* a_hbuf = hbuf;
  unsigned* a_cnt = cnt;
  const float* a_bf = (const float*)d_in[16];
  const float* a_bo = (const float*)d_in[18];
  const float* a_bc = (const float*)d_in[19];
  float* a_out = (float*)d_out;
  void* kargs[10] = { (void*)&a_ubf, (void*)&a_xgo, (void*)&a_xgc, (void*)&a_xgfl,
                      (void*)&a_hbuf, (void*)&a_cnt, (void*)&a_bf, (void*)&a_bo,
                      (void*)&a_bc, (void*)&a_out };
  hipError_t ce = hipLaunchCooperativeKernel((const void*)k_recur, dim3(256), dim3(256),
                                             kargs, 0, stream);
  if (ce != hipSuccess) {
    // fallback: plain launch (256 blocks of 4 waves @ <=512 VGPR -> 1/CU, all co-resident)
    hipLaunchKernelGGL(k_recur, dim3(256), dim3(256), 0, stream,
                       ubf, xgo, xgc, xgfl, hbuf, cnt, a_bf, a_bo, a_bc, a_out);
  }
}

// Round 2
// 4626.419 us; speedup vs baseline: 9.3634x; 9.3634x over previous
//
#include <hip/hip_runtime.h>
#include <hip/hip_bf16.h>

// MaskedLSTM: B=128 S=1024 I=512 H=512
// out = [B,S,H] f32  ++  hT [1,B,H] f32  ++  cT [1,B,H] f32
//
// Design:
//  - i-gate is computed but UNUSED in the reference -> skip Wi/Wi_m/Ui/Ui_m/bi.
//  - Hoist x-projections: xg_g[b,t,:] = sigmoid(x W_m^T) * (x W^T)  (3 pairs: f,o,c), bf16 MFMA.
//  - Recurrence: persistent kernel, 16 teams x 16 blocks; block owns 8 batch rows x 32 cols.
//    h exchanged via FINE-GRAINED AGENT-SCOPE ATOMICS (LLC point-coherent, no L2 fences).
//    Round-1 lesson: __threadfence() per step = full L2 wb/inv sweep = 41 us/step. Removed.

typedef __attribute__((ext_vector_type(8))) short short8;
typedef __attribute__((ext_vector_type(4))) float floatx4;
typedef unsigned short ushort_t;

static constexpr size_t kMat   = 512 * 512;              // 262144 elems
static constexpr size_t O_W    = 0;                      // 12 mats bf16: 6291456 B
static constexpr size_t O_XGO  = 12 * kMat * 2;          // 6291456
static constexpr size_t O_XGC  = O_XGO + 134217728ull;   // 140509184
static constexpr size_t O_XGF  = O_XGC + 134217728ull;   // 274726912 (last-step xg_f, B*H bf16)
static constexpr size_t O_HB   = O_XGF + 131072ull;      // 274857984 (h exchange, u32 view)
static constexpr size_t O_CNT  = O_HB + 524288ull;       // 275382272 (16*1024 u32)
static constexpr size_t WS_NEED = O_CNT + 65536ull;      // ~263 MB

__device__ __forceinline__ ushort_t f2bf(float f) {
  unsigned u = __float_as_uint(f);
  u = (u + 0x7FFFu + ((u >> 16) & 1u)) >> 16;
  return (ushort_t)u;
}
__device__ __forceinline__ float bf2f(ushort_t h) {
  return __uint_as_float(((unsigned)h) << 16);
}
__device__ __forceinline__ float sigf(float x) { return 1.0f / (1.0f + __expf(-x)); }

struct Ptrs12 { const float* p[12]; };

// ---------------- prep: weights fp32->bf16, zero hbuf+cnt ----------------
__global__ void k_prep(Ptrs12 a, ushort_t* __restrict__ wbf, unsigned* __restrict__ zr) {
  unsigned idx = blockIdx.x * 256u + threadIdx.x;
  const unsigned WTOT = 12u * 262144u;
  if (idx < WTOT) {
    wbf[idx] = f2bf(a.p[idx >> 18][idx & 262143u]);
  } else {
    zr[idx - WTOT] = 0u;  // grid sized exactly: (WTOT + 147456)/256 blocks
  }
}

// ---------------- x-projection masked-linear GEMM ----------------
// grid (1024, 4, 3): M-tile 128, N-tile 128, pair p in {f,o,c}
__global__ __launch_bounds__(256, 2) void k_xgemm(
    const float* __restrict__ x, const ushort_t* __restrict__ wbf,
    ushort_t* __restrict__ xgo, ushort_t* __restrict__ xgc,
    ushort_t* __restrict__ xgf_last, ushort_t* out_xgf) {
  __shared__ ushort_t At[128][64];
  __shared__ ushort_t Bt[2][128][64];
  const int p  = blockIdx.z;
  const int R0 = blockIdx.x * 128;
  const int n0 = blockIdx.y * 128;
  const ushort_t* Wmain = wbf + (size_t)(2 * p) * kMat;
  const ushort_t* Wmask = wbf + (size_t)(2 * p + 1) * kMat;
  const int tid = threadIdx.x;
  const int lane = tid & 63, w = tid >> 6;
  const int wr = w >> 1, wc = w & 1;
  const int sr = tid >> 1, sh = tid & 1;

  floatx4 accM[4][4], accK[4][4];
#pragma unroll
  for (int mt = 0; mt < 4; ++mt)
#pragma unroll
    for (int nt = 0; nt < 4; ++nt) {
      accM[mt][nt] = (floatx4){0.f, 0.f, 0.f, 0.f};
      accK[mt][nt] = (floatx4){0.f, 0.f, 0.f, 0.f};
    }

  for (int kb = 0; kb < 8; ++kb) {
    __syncthreads();
    // stage A: x fp32 -> bf16
    const float* xa = x + (size_t)(R0 + sr) * 512 + kb * 64 + sh * 32;
#pragma unroll
    for (int q = 0; q < 4; ++q) {
      float4 v0 = *reinterpret_cast<const float4*>(xa + q * 8);
      float4 v1 = *reinterpret_cast<const float4*>(xa + q * 8 + 4);
      short8 s;
      s[0] = (short)f2bf(v0.x); s[1] = (short)f2bf(v0.y);
      s[2] = (short)f2bf(v0.z); s[3] = (short)f2bf(v0.w);
      s[4] = (short)f2bf(v1.x); s[5] = (short)f2bf(v1.y);
      s[6] = (short)f2bf(v1.z); s[7] = (short)f2bf(v1.w);
      *reinterpret_cast<short8*>(&At[sr][sh * 32 + q * 8]) = s;
    }
    // stage B: both weight matrices (already bf16)
#pragma unroll
    for (int m2 = 0; m2 < 2; ++m2) {
      const ushort_t* src = (m2 ? Wmask : Wmain) + (size_t)(n0 + sr) * 512 + kb * 64 + sh * 32;
#pragma unroll
      for (int q = 0; q < 4; ++q)
        *reinterpret_cast<short8*>(&Bt[m2][sr][sh * 32 + q * 8]) =
            *reinterpret_cast<const short8*>(src + q * 8);
    }
    __syncthreads();
#pragma unroll
    for (int ks = 0; ks < 2; ++ks) {
      const int ko = ks * 32 + (lane >> 4) * 8;
      short8 a[4], b0[4], b1[4];
#pragma unroll
      for (int mt = 0; mt < 4; ++mt)
        a[mt] = *reinterpret_cast<const short8*>(&At[wr * 64 + mt * 16 + (lane & 15)][ko]);
#pragma unroll
      for (int nt = 0; nt < 4; ++nt) {
        b0[nt] = *reinterpret_cast<const short8*>(&Bt[0][wc * 64 + nt * 16 + (lane & 15)][ko]);
        b1[nt] = *reinterpret_cast<const short8*>(&Bt[1][wc * 64 + nt * 16 + (lane & 15)][ko]);
      }
#pragma unroll
      for (int mt = 0; mt < 4; ++mt)
#pragma unroll
        for (int nt = 0; nt < 4; ++nt) {
          accM[mt][nt] = __builtin_amdgcn_mfma_f32_16x16x32_bf16(a[mt], b0[nt], accM[mt][nt], 0, 0, 0);
          accK[mt][nt] = __builtin_amdgcn_mfma_f32_16x16x32_bf16(a[mt], b1[nt], accK[mt][nt], 0, 0, 0);
        }
    }
  }
  // epilogue: sigmoid(mask) * main, store bf16
#pragma unroll
  for (int mt = 0; mt < 4; ++mt)
#pragma unroll
    for (int nt = 0; nt < 4; ++nt)
#pragma unroll
      for (int r = 0; r < 4; ++r) {
        float val = sigf(accK[mt][nt][r]) * accM[mt][nt][r];
        int row = R0 + wr * 64 + mt * 16 + (lane >> 4) * 4 + r;   // flattened b*S+t
        int col = n0 + wc * 64 + nt * 16 + (lane & 15);
        ushort_t bv = f2bf(val);
        if (p == 1) {
          xgo[(size_t)row * 512 + col] = bv;
        } else if (p == 2) {
          xgc[(size_t)row * 512 + col] = bv;
        } else {
          int t = row & 1023;
          if (t == 1023) xgf_last[(row >> 10) * 512 + col] = bv;
          else out_xgf[(size_t)(row + 1) * 1024 + 512 + col] = bv;  // upper half of f32 slot t+1
        }
      }
}

// ---------------- recurrence: persistent, 16 teams x 16 blocks, fence-free ----------------
__global__ __launch_bounds__(256, 1) void k_recur(
    const ushort_t* __restrict__ ubf,
    const ushort_t* __restrict__ xgo, const ushort_t* __restrict__ xgc,
    const ushort_t* __restrict__ xgf_last,
    unsigned* hbuf, unsigned* cnt,
    const float* __restrict__ bfp, const float* __restrict__ bop, const float* __restrict__ bcp,
    float* out) {
  __shared__ ushort_t htile[16][520];   // padded: row stride 1040 B -> balanced banks for b128
  __shared__ float comb[12][8][16];
  const int bid = blockIdx.x;
  const int team = bid >> 4;     // 16 teams of 8 batch rows
  const int member = bid & 15;   // 16 blocks/team, 32 cols each
  const int tid = threadIdx.x;
  const int lane = tid & 63, w = tid >> 6;

  // ---- resident U weight fragments: wave w owns chunks {w, w+4, w+8} ----
  short8 uw[3][16];
#pragma unroll
  for (int i = 0; i < 3; ++i) {
    const int c = w + 4 * i;
    const int m = c % 6, ct = c / 6;
    const int row = member * 32 + ct * 16 + (lane & 15);
    const ushort_t* src = ubf + (size_t)m * kMat + (size_t)row * 512 + (lane >> 4) * 8;
#pragma unroll
    for (int kf = 0; kf < 16; ++kf)
      uw[i][kf] = *reinterpret_cast<const short8*>(src + kf * 32);
  }

  // zero pad rows 8..15 of htile once (h rows 8..15 are structural zeros)
  {
    unsigned* hrow = reinterpret_cast<unsigned*>(&htile[8 + (tid >> 5)][0]) + (tid & 31) * 8;
#pragma unroll
    for (int q = 0; q < 8; ++q) hrow[q] = 0u;
    // pad columns (512..519) of all rows
    if (tid < 64) {
      reinterpret_cast<unsigned*>(&htile[tid >> 2][512])[tid & 3] = 0u;
    }
  }

  // elementwise identity: thread -> (row er, col ej)
  const int er = tid >> 5;          // 0..7
  const int ej = tid & 31;          // 0..31
  const int ect = ej >> 4, ejj = ej & 15;
  const int col = member * 32 + ej;
  const int b = team * 8 + er;
  const float bfv = bfp[col], bov = bop[col], bcv = bcp[col];
  float cp = 0.0f;

  unsigned* hb = hbuf + (size_t)team * (2 * 8 * 256);   // [2][8][256] u32 of bf16-pairs
  unsigned* tcnt = cnt + team * 1024;
  const ushort_t* out_us = reinterpret_cast<const ushort_t*>(out);
  int cur = 0;

  for (int t = 0; t < 1024; ++t) {
    // ---- pull h(t) from LLC via agent-scope atomic loads, stage to LDS ----
    {
      const unsigned* hsrc = hb + cur * (8 * 256) + (tid >> 5) * 256 + (tid & 31) * 8;
      unsigned hv8[8];
#pragma unroll
      for (int q = 0; q < 8; ++q)
        hv8[q] = __hip_atomic_load(hsrc + q, __ATOMIC_RELAXED, __HIP_MEMORY_SCOPE_AGENT);
      unsigned* hdst = reinterpret_cast<unsigned*>(&htile[tid >> 5][0]) + (tid & 31) * 8;
#pragma unroll
      for (int q = 0; q < 8; ++q) hdst[q] = hv8[q];
    }
    // prefetch x-projections (independent of h; hide HBM/L2 latency under MFMA)
    const size_t bt = (size_t)b * 1024 + t;
    float xov = bf2f(xgo[bt * 512 + col]);
    float xcv = bf2f(xgc[bt * 512 + col]);
    float xfv = (t == 1023) ? bf2f(xgf_last[b * 512 + col])
                            : bf2f(out_us[(bt + 1) * 1024 + 512 + col]);
    __syncthreads();

    // A fragments from LDS
    short8 af[16];
    {
      const ushort_t* abase = &htile[lane & 15][(lane >> 4) * 8];
#pragma unroll
      for (int kf = 0; kf < 16; ++kf)
        af[kf] = *reinterpret_cast<const short8*>(abase + kf * 32);
    }

    floatx4 acc[3];
#pragma unroll
    for (int i = 0; i < 3; ++i) acc[i] = (floatx4){0.f, 0.f, 0.f, 0.f};
#pragma unroll
    for (int kf = 0; kf < 16; ++kf)
#pragma unroll
      for (int i = 0; i < 3; ++i)
        acc[i] = __builtin_amdgcn_mfma_f32_16x16x32_bf16(af[kf], uw[i][kf], acc[i], 0, 0, 0);

    // scatter acc rows 0..7 to LDS for the pair-combine
    if (lane < 32) {
      const int rr = (lane >> 4) * 4;
#pragma unroll
      for (int i = 0; i < 3; ++i) {
        const int c = w + 4 * i;
#pragma unroll
        for (int r = 0; r < 4; ++r) comb[c][rr + r][lane & 15] = acc[i][r];
      }
    }
    __syncthreads();

    const float hUf  = comb[ect * 6 + 0][er][ejj];
    const float hUfm = comb[ect * 6 + 1][er][ejj];
    const float hUo  = comb[ect * 6 + 2][er][ejj];
    const float hUom = comb[ect * 6 + 3][er][ejj];
    const float hUc  = comb[ect * 6 + 4][er][ejj];
    const float hUcm = comb[ect * 6 + 5][er][ejj];

    const float fg = sigf(sigf(hUfm) * hUf + xfv + bfv);
    const float og = sigf(sigf(hUom) * hUo + xov + bov);
    const float cn = fg * cp + tanhf(sigf(hUcm) * hUc + xcv + bcv);
    const float hv = og * cn;
    cp = cn;

    out[bt * 512 + col] = hv;                       // y (overwrites consumed xg_f slot)
    // ---- publish h(t+1): packed bf16-pair, agent-scope write-through ----
    {
      unsigned mine = (unsigned)f2bf(hv);
      unsigned other = (unsigned)__shfl_xor((int)mine, 1);
      if ((ej & 1) == 0) {
        unsigned packed = mine | (other << 16);
        __hip_atomic_store(hb + (cur ^ 1) * (8 * 256) + er * 256 + (col >> 1), packed,
                           __ATOMIC_RELAXED, __HIP_MEMORY_SCOPE_AGENT);
      }
    }
    if (t == 1023) {
      out[67108864ull + (size_t)b * 512 + col] = hv;            // hT
      out[67108864ull + 65536ull + (size_t)b * 512 + col] = cn; // cT
    }

    // ---- team barrier: drain stores, arrive, poll (RMW = guaranteed coherent) ----
    asm volatile("s_waitcnt vmcnt(0)" ::: "memory");
    __syncthreads();
    if (tid == 0) {
      __hip_atomic_fetch_add(&tcnt[t], 1u, __ATOMIC_RELAXED, __HIP_MEMORY_SCOPE_AGENT);
      while (__hip_atomic_fetch_add(&tcnt[t], 0u, __ATOMIC_RELAXED, __HIP_MEMORY_SCOPE_AGENT) < 16u)
        __builtin_amdgcn_s_sleep(2);
    }
    __syncthreads();
    cur ^= 1;
  }
}

extern "C" void kernel_launch(void* const* d_in, const int* in_sizes, int n_in,
                              void* d_out, int out_size, void* d_ws, size_t ws_size,
                              hipStream_t stream) {
  (void)in_sizes; (void)n_in; (void)out_size; (void)ws_size;
  // d_in order: 0 Wf,1 Wf_m,2 Wi,3 Wi_m,4 Wo,5 Wo_m,6 Wc,7 Wc_m,
  //             8 Uf,9 Uf_m,10 Ui,11 Ui_m,12 Uo,13 Uo_m,14 Uc,15 Uc_m,
  //             16 bf,17 bi,18 bo,19 bc, 20 x
  char* ws = (char*)d_ws;
  ushort_t* wbf = (ushort_t*)(ws + O_W);
  const ushort_t* ubf = wbf + 6 * kMat;
  ushort_t* xgo = (ushort_t*)(ws + O_XGO);
  ushort_t* xgc = (ushort_t*)(ws + O_XGC);
  ushort_t* xgfl = (ushort_t*)(ws + O_XGF);
  unsigned* hbuf = (unsigned*)(ws + O_HB);
  unsigned* cnt = (unsigned*)(ws + O_CNT);

  Ptrs12 pa;
  pa.p[0] = (const float*)d_in[0];  pa.p[1] = (const float*)d_in[1];   // Wf, Wf_m
  pa.p[2] = (const float*)d_in[4];  pa.p[3] = (const float*)d_in[5];   // Wo, Wo_m
  pa.p[4] = (const float*)d_in[6];  pa.p[5] = (const float*)d_in[7];   // Wc, Wc_m
  pa.p[6] = (const float*)d_in[8];  pa.p[7] = (const float*)d_in[9];   // Uf, Uf_m
  pa.p[8] = (const float*)d_in[12]; pa.p[9] = (const float*)d_in[13];  // Uo, Uo_m
  pa.p[10] = (const float*)d_in[14]; pa.p[11] = (const float*)d_in[15]; // Uc, Uc_m

  hipLaunchKernelGGL(k_prep, dim3((12u * 262144u + 147456u) / 256u), dim3(256), 0, stream,
                     pa, wbf, (unsigned*)(ws + O_HB));
  hipLaunchKernelGGL(k_xgemm, dim3(1024, 4, 3), dim3(256), 0, stream,
                     (const float*)d_in[20], wbf, xgo, xgc, xgfl, (ushort_t*)d_out);

  const ushort_t* a_ubf = ubf;
  const ushort_t* a_xgo = xgo;
  const ushort_t* a_xgc = xgc;
  const ushort_t* a_xgfl = xgfl;
  unsigned* a_hbuf = hbuf;
  unsigned* a_cnt = cnt;
  const float* a_bf = (const float*)d_in[16];
  const float* a_bo = (const float*)d_in[18];
  const float* a_bc = (const float*)d_in[19];
  float* a_out = (float*)d_out;
  void* kargs[10] = { (void*)&a_ubf, (void*)&a_xgo, (void*)&a_xgc, (void*)&a_xgfl,
                      (void*)&a_hbuf, (void*)&a_cnt, (void*)&a_bf, (void*)&a_bo,
                      (void*)&a_bc, (void*)&a_out };
  hipError_t ce = hipLaunchCooperativeKernel((const void*)k_recur, dim3(256), dim3(256),
                                             kargs, 0, stream);
  if (ce != hipSuccess) {
    // fallback: plain launch (256 blocks, 1 block/CU, all co-resident)
    hipLaunchKernelGGL(k_recur, dim3(256), dim3(256), 0, stream,
                       ubf, xgo, xgc, xgfl, hbuf, cnt, a_bf, a_bo, a_bc, a_out);
  }
}